// Round 1
// baseline (47.700 us; speedup 1.0000x reference)
//
#include <hip/hip_runtime.h>

// out[c][b] = sum_m in[b][c][m] * W[c][m]
// in : [BATCH, NCLS, NMOD] f32  (NMOD=4 contiguous -> float4 per (b,c))
// W  : [NCLS, NMOD] f32
// out: [NCLS, BATCH, 1] f32 -> flat c*BATCH + b

#define BATCH   32768
#define NCLS    400
#define NMOD    4
#define BT      32          // batch rows per block
#define PAD     1
#define THREADS 256

__global__ __launch_bounds__(THREADS) void fusion_class_layer_kernel(
    const float* __restrict__ in,   // [B, C, 4]
    const float* __restrict__ W,    // [C, 4]
    float* __restrict__ out)        // [C, B]
{
    __shared__ float lds[NCLS * (BT + PAD)];   // ~52.8 KB

    const int b0  = blockIdx.x * BT;
    const int tid = threadIdx.x;

    // Phase 1: coalesced float4 loads (c fastest), dot with W[c], transpose into LDS.
    // BT*NCLS = 12800 elements, 50 iterations of 256 threads.
    for (int idx = tid; idx < BT * NCLS; idx += THREADS) {
        const int b_local = idx / NCLS;
        const int c       = idx - b_local * NCLS;
        const float4 v = *reinterpret_cast<const float4*>(
            in + ((b0 + b_local) * NCLS + c) * NMOD);
        const float4 w = *reinterpret_cast<const float4*>(W + c * NMOD);
        lds[c * (BT + PAD) + b_local] =
            v.x * w.x + v.y * w.y + v.z * w.z + v.w * w.w;
    }

    __syncthreads();

    // Phase 2: coalesced writes (b fastest within each class row).
    for (int idx = tid; idx < BT * NCLS; idx += THREADS) {
        const int c       = idx >> 5;          // idx / BT (BT=32)
        const int b_local = idx & (BT - 1);    // idx % BT
        out[c * BATCH + b0 + b_local] = lds[c * (BT + PAD) + b_local];
    }
}

extern "C" void kernel_launch(void* const* d_in, const int* in_sizes, int n_in,
                              void* d_out, int out_size, void* d_ws, size_t ws_size,
                              hipStream_t stream) {
    const float* in  = (const float*)d_in[0];   // logit_concat [32768,400,4]
    const float* W   = (const float*)d_in[1];   // [400,4]
    float*       out = (float*)d_out;           // [400,32768,1]

    const int grid = BATCH / BT;                // 1024 blocks
    fusion_class_layer_kernel<<<grid, THREADS, 0, stream>>>(in, W, out);
}